// Round 15
// baseline (121.325 us; speedup 1.0000x reference)
//
#include <hip/hip_runtime.h>
#include <hip/hip_cooperative_groups.h>

#pragma clang fp contract(off)

namespace {
constexpr int NB = 2, ND = 100, MH = 28, MW = 28;
constexpr int OH = 512, OW = 512;
constexpr int SH = 128, SW = 128, NC = 32;
constexpr int BMP_ROWS = 172;
constexpr int BMP8_ROWWORDS = 8;                        // canvas-aligned words per row (even q0)
constexpr int BMP8_DETWORDS = BMP_ROWS * BMP8_ROWWORDS; // 1376

// workspace layout (int32 word indices)
constexpr int OFF_COUNTS = 0;                     // NB*32
constexpr int OFF_AREA   = 64;                    // NB*ND
constexpr int OFF_ACC    = OFF_AREA + NB*ND;
constexpr int OFF_YB     = OFF_ACC  + NB*ND;
constexpr int OFF_VAL    = OFF_YB   + NB*ND;
constexpr int OFF_QN     = OFF_VAL  + NB*ND;
constexpr int OFF_FLAG   = OFF_QN   + NB*ND;      // scan-done flag (clock-warming spin)
constexpr int OFF_SEGCLS = OFF_FLAG + 4;          // byte region: NB*OH*OW bytes
constexpr int OFF_BMP8   = OFF_SEGCLS + (NB*OH*OW)/4;
constexpr int OCC_STRIDE = 26;                    // EVEN -> 8B-aligned u64 cells; q0e+7 <= 21 < 26
constexpr int OCC_STRIDE2 = OCC_STRIDE/2;         // 13 u64 per row (odd -> 2-way conflict = free)
constexpr int OCC_WORDS  = OH * OCC_STRIDE;       // 13312 words = 53.2 KB
constexpr int SEGW_TOTAL = (NB*OH*OW)/4;          // 131072 segcls words
constexpr int NHIST      = 128;                   // histogram/warming blocks inside k_scan
constexpr int HIST_WORDS = SEGW_TOTAL / NHIST;    // 1024 words per hist block
static_assert(OFF_BMP8 % 4 == 0, "16B alignment");

struct SegSh  { float patch[NC*342]; };                          // 43.8 KB
struct MaskSh { float sc[ND]; float sm[MH*MW]; int det; int area; };
union  K1Sh   { SegSh seg; MaskSh mask; };
}

// ---------------- seg tile: 64x64 out px, 1024 thr (1 row x 4 col per thread) ----------------
__device__ __forceinline__ void segTile(int tid, int t, const float* __restrict__ segp,
                                        int* __restrict__ wsI, int* __restrict__ out,
                                        SegSh& S) {
  const int b  = tid >> 6;
  const int tl = tid & 63;
  const int oy = (tl >> 3) * 64, ox = (tl & 7) * 64;
  const int iy0 = (oy >> 2) - 1, ix0 = (ox >> 2) - 1;
  // stage patch: 18x18 px x 8 float4
  for (int idx = t; idx < 18*18*8; idx += 1024) {
    const int w  = idx & 7, px = idx >> 3;
    const int pr = px / 18, pc = px - pr*18;
    const int gy = min(max(iy0 + pr, 0), SH-1);
    const int gx = min(max(ix0 + pc, 0), SW-1);
    const float4 v = *(const float4*)(segp + (size_t)((b*SH + gy)*SW + gx)*NC + w*4);
    const int base = pr*19 + pc;
    S.patch[(w*4+0)*342 + base] = v.x;
    S.patch[(w*4+1)*342 + base] = v.y;
    S.patch[(w*4+2)*342 + base] = v.z;
    S.patch[(w*4+3)*342 + base] = v.w;
  }
  __syncthreads();
  const int ry = t >> 4;                 // 0..63 output row within tile
  const int cq = t & 15;                 // 0..15 col quad
  const int Y = oy + ry;
  // y table (weights exact eighths; clamp -> f=0 single-tap exact)
  float my = ((float)Y + 0.5f)*0.25f - 0.5f;
  float y0f = floorf(my);
  float fy = my - y0f;
  int y0 = (int)y0f, y1 = y0 + 1;
  if (y0 < 0)           { y0 = 0; y1 = 0; fy = 0.0f; }
  else if (y1 > SH - 1) { y1 = SH - 1; fy = 0.0f; }
  const float wy = 1.0f - fy;
  const int ro0 = (y0 - iy0)*19, ro1 = (y1 - iy0)*19;
  // col tables; v01 share x0/x1, v23 share (holds under edge clamps too)
  int co[4]; float fx[4], wx[4];
  {
    int clo[4], chi[4];
    #pragma unroll
    for (int v = 0; v < 4; ++v) {
      const int X = ox + cq*4 + v;
      float mx = ((float)X + 0.5f)*0.25f - 0.5f;
      float x0f = floorf(mx);
      float f = mx - x0f;
      int x0 = (int)x0f, x1 = x0 + 1;
      if (x0 < 0)           { x0 = 0; x1 = 0; f = 0.0f; }
      else if (x1 > SW - 1) { x1 = SW - 1; f = 0.0f; }
      clo[v] = x0 - ix0; chi[v] = x1 - ix0; fx[v] = f; wx[v] = 1.0f - f;
    }
    co[0] = clo[0]; co[1] = chi[0]; co[2] = clo[2]; co[3] = chi[2];
  }
  float best[4]; int bcls[4];
  #pragma unroll
  for (int v = 0; v < 4; ++v) { best[v] = -3.4e38f; bcls[v] = 0; }
  for (int ch = 0; ch < NC; ++ch) {
    const float* P = S.patch + ch*342;
    const float t0 = P[ro0 + co[0]], t1 = P[ro0 + co[1]];
    const float t2 = P[ro0 + co[2]], t3 = P[ro0 + co[3]];
    const float b0 = P[ro1 + co[0]], b1 = P[ro1 + co[1]];
    const float b2 = P[ro1 + co[2]], b3 = P[ro1 + co[3]];
    const float V0 = wy*t0 + fy*b0;      // vertical first (matches ref/XLA dim order)
    const float V1 = wy*t1 + fy*b1;
    const float V2 = wy*t2 + fy*b2;
    const float V3 = wy*t3 + fy*b3;
    const float v0 = wx[0]*V0 + fx[0]*V1;
    const float v1 = wx[1]*V0 + fx[1]*V1;
    const float v2 = wx[2]*V2 + fx[2]*V3;
    const float v3 = wx[3]*V2 + fx[3]*V3;
    if (v0 > best[0]) { best[0] = v0; bcls[0] = ch; }   // strict > = first max
    if (v1 > best[1]) { best[1] = v1; bcls[1] = ch; }
    if (v2 > best[2]) { best[2] = v2; bcls[2] = ch; }
    if (v3 > best[3]) { best[3] = v3; bcls[3] = ch; }
  }
  unsigned int* segclsW = (unsigned int*)((char*)wsI + (size_t)OFF_SEGCLS*4);
  const int X0 = ox + cq*4;
  const int pidw = (b*OH*OW + Y*OW + X0) >> 2;
  segclsW[pidw] = (unsigned)bcls[0] | ((unsigned)bcls[1]<<8)
                | ((unsigned)bcls[2]<<16) | ((unsigned)bcls[3]<<24);
  const uint4 sent = uint4{0x7FFFFFFFu,0x7FFFFFFFu,0x7FFFFFFFu,0x7FFFFFFFu};
  *(uint4*)(out + b*OH*OW + Y*OW + X0) = sent;          // owner sentinel
}

// ---------------- mask: per-det bitmap + area, 4 rows per iteration (even-aligned q0) ----------------
__device__ __forceinline__ void maskOne(int g, int t, const float* __restrict__ boxes,
                                        const int* __restrict__ classes,
                                        const float* __restrict__ scores,
                                        const float* __restrict__ dmasks,
                                        int* __restrict__ wsI, MaskSh& M) {
  const int b = g / ND, k = g - b*ND;
  if (t < ND) M.sc[t] = scores[b*ND + t];
  if (t == 0) M.area = 0;
  __syncthreads();
  if (t < ND) {
    float sn = M.sc[t];
    int r = 0;
    for (int j = 0; j < ND; ++j) {
      float sj = M.sc[j];
      r += (sj > sn) || (sj == sn && j < t);   // stable descending rank
    }
    if (r == k) M.det = t;
  }
  __syncthreads();
  const int det = M.det;
  const int cls = classes[b*ND + det];
  const float sc = M.sc[det];
  const float* bx = boxes + (size_t)(b*ND + det)*4;
  const float ymin = bx[0], xmin = bx[1], ymax = bx[2], xmax = bx[3];
  const bool keep = (sc > 0.5f) && (cls != 0);
  int ylo = (int)ceilf(ymin), yhi = (int)ceilf(ymax);
  int xlo = (int)ceilf(xmin), xhi = (int)ceilf(xmax);
  ylo = max(ylo, 0); xlo = max(xlo, 0);
  yhi = min(yhi, OH); xhi = min(xhi, OW);
  if (yhi < ylo) yhi = ylo;
  if (xhi < xlo) xhi = xlo;
  if (yhi - ylo > BMP_ROWS) yhi = ylo + BMP_ROWS;
  if (xhi - xlo > 192)      xhi = xlo + 192;
  const int yhi2 = keep ? yhi : ylo, xhi2 = keep ? xhi : xlo;
  const int rows = yhi2 - ylo, width = xhi2 - xlo;
  const int q0 = (xlo >> 5) & ~1;      // EVEN canvas word; span <= 63+192=255 bits <= 8 words
  const int nw = (width > 0) ? (((xlo - (q0 << 5)) + width + 31) >> 5) : 0;  // <= 8
  if (t == 0) {
    wsI[OFF_YB  + g] = ylo | (yhi2 << 16);
    wsI[OFF_VAL + g] = (det + 1) | (cls << 16);
    wsI[OFF_QN  + g] = q0 | (nw << 16);
  }
  if (rows > 0 && width > 0) {
    const float hs  = (ymax > ymin) ? (28.0f / (ymax - ymin)) : 0.0f;
    const float wsc = (xmax > xmin) ? (28.0f / (xmax - xmin)) : 0.0f;
    const float* mp = dmasks + (size_t)(b*ND + det)*(MH*MW);
    for (int i = t; i < MH*MW; i += 1024) M.sm[i] = mp[i];
    __syncthreads();
    unsigned int* bmp8 = (unsigned int*)wsI + OFF_BMP8 + g*BMP8_DETWORDS;
    const int rq = t >> 8;               // row quarter 0..3 (wave-uniform)
    const int px = t & 255;
    const int iw = px >> 5, bit = px & 31;
    const int x = ((q0 + iw) << 5) + bit;
    const bool inbox = (x >= xlo) && (x < xhi2);
    for (int r = rq; r < rows; r += 4) {
      const int y = ylo + r;
      bool pred = false;
      if (inbox) {
        // exact op order of _paste_one (fp contract off)
        float ty = ((float)y + 0.5f); ty = ty - ymin; ty = ty * hs;  float my = ty - 0.5f;
        float tx = ((float)x + 0.5f); tx = tx - xmin; tx = tx * wsc; float mx = tx - 0.5f;
        float y0f = floorf(my), x0f = floorf(mx);
        float ly = my - y0f, lx = mx - x0f;
        int y0 = (int)y0f, x0 = (int)x0f;
        int y1 = min(max(y0 + 1, 0), MH - 1);
        int x1 = min(max(x0 + 1, 0), MW - 1);
        y0 = min(max(y0, 0), MH - 1);
        x0 = min(max(x0, 0), MW - 1);
        float v00 = M.sm[y0*MW + x0], v01 = M.sm[y0*MW + x1];
        float v10 = M.sm[y1*MW + x0], v11 = M.sm[y1*MW + x1];
        float omlx = 1.0f - lx, omly = 1.0f - ly;
        float top = omlx*v00 + lx*v01;
        float bot = omlx*v10 + lx*v11;
        float outv = omly*top + ly*bot;
        pred = outv > 0.5f;
      }
      unsigned long long m = __ballot(pred);
      unsigned int word = (px & 32) ? (unsigned int)(m >> 32) : (unsigned int)m;
      if (bit == 0) {
        bmp8[r*BMP8_ROWWORDS + iw] = word;
        if (word) atomicAdd(&M.area, __popc(word));
      }
    }
  }
  __syncthreads();
  if (t == 0) wsI[OFF_AREA + g] = (rows > 0 && width > 0) ? M.area : 0;
}

// ================= K1: tiled seg (blocks 0..127) + masks (blocks 128..327) =================
__global__ void __launch_bounds__(1024) k_segmask(
    const float* __restrict__ boxes, const int* __restrict__ classes,
    const float* __restrict__ scores, const float* __restrict__ dmasks,
    const float* __restrict__ segp, int* __restrict__ wsI, int* __restrict__ out) {
  __shared__ K1Sh sh;
  const int bid = blockIdx.x, t = threadIdx.x;
  if (bid == 0 && t < 2*NC) wsI[OFF_COUNTS + t] = 0;   // zero class counters (used next kernel)
  if (bid == 0 && t == 2*NC) wsI[OFF_FLAG] = 0;        // zero scan-done flag
  if (bid < 128) segTile(bid, t, segp, wsI, out, sh.seg);
  else           maskOne(bid - 128, t, boxes, classes, scores, dmasks, wsI, sh.mask);
}

// ================= K2: scan (blocks 0..1, u64 occ) + histogram/clock-warming (2..129) =================
namespace {
struct DetReg {
  int g, q2, yb, thr;
  ulonglong2 r0a, r0b, r1a, r1b, r2a, r2b;   // per row-quarter: a=words0-3, b=words4-7
};
}

__device__ __forceinline__ void fetchD(int yb, int aux, int t,
                                       const ulonglong2* __restrict__ bmp2, DetReg& D) {
  D.yb  = yb;
  const int q0e = aux & 15;
  D.q2  = q0e >> 1;
  D.g   = (aux >> 4) & 127;
  D.thr = aux >> 11;
  const int rows = (yb >> 16) - (yb & 0xffff);
  const ulonglong2* p = bmp2 + (size_t)D.g*(BMP8_DETWORDS/4);
  const ulonglong2 z = ulonglong2{0ull, 0ull};
  D.r0a = z; D.r0b = z; D.r1a = z; D.r1b = z; D.r2a = z; D.r2b = z;
  if (t < rows)       { D.r0a = p[t*2];         D.r0b = p[t*2 + 1]; }
  if (t + 64 < rows)  { D.r1a = p[(t+64)*2];    D.r1b = p[(t+64)*2 + 1]; }
  if (t + 128 < rows) { D.r2a = p[(t+128)*2];   D.r2b = p[(t+128)*2 + 1]; }
}

__device__ __forceinline__ int quarterCount(const ulonglong2& a, const ulonglong2& b,
                                            bool valid, int rb2,
                                            const unsigned long long* occ64,
                                            unsigned long long o[4]) {
  int c = 0;
  if (valid) {
    o[0] = occ64[rb2+0]; o[1] = occ64[rb2+1]; o[2] = occ64[rb2+2]; o[3] = occ64[rb2+3];
    c += __popcll(a.x & o[0]); c += __popcll(a.y & o[1]);
    c += __popcll(b.x & o[2]); c += __popcll(b.y & o[3]);
  }
  return c;
}

__device__ __forceinline__ void quarterWrite(const ulonglong2& a, const ulonglong2& b,
                                             bool valid, int rb2,
                                             unsigned long long* occ64,
                                             const unsigned long long o[4]) {
  if (valid) {
    occ64[rb2+0] = o[0] | a.x; occ64[rb2+1] = o[1] | a.y;
    occ64[rb2+2] = o[2] | b.x; occ64[rb2+3] = o[3] | b.y;
  }
}

__device__ __forceinline__ int waveSum63(int cnt) {
  // 64-lane sum via DPP (row_shr 1/2/4/8 + row_bcast15/31); total lands in lane 63
  cnt += __builtin_amdgcn_update_dpp(0, cnt, 0x111, 0xF, 0xF, false);
  cnt += __builtin_amdgcn_update_dpp(0, cnt, 0x112, 0xF, 0xF, false);
  cnt += __builtin_amdgcn_update_dpp(0, cnt, 0x114, 0xF, 0xF, false);
  cnt += __builtin_amdgcn_update_dpp(0, cnt, 0x118, 0xF, 0xF, false);
  cnt += __builtin_amdgcn_update_dpp(0, cnt, 0x142, 0xF, 0xF, false);
  cnt += __builtin_amdgcn_update_dpp(0, cnt, 0x143, 0xF, 0xF, false);
  return __builtin_amdgcn_readlane(cnt, 63);
}

__device__ __forceinline__ void processDet(int t, const DetReg& D,
                                           unsigned long long* occ64,
                                           int* __restrict__ accB) {
  const int ylo = D.yb & 0xffff;
  const int rows = (D.yb >> 16) - ylo;
  const bool v0 = t < rows, v1 = t + 64 < rows, v2 = t + 128 < rows;
  const int rb0 = (ylo + t) * OCC_STRIDE2 + D.q2;
  const int rb1 = rb0 + 64*OCC_STRIDE2;
  const int rb2 = rb0 + 128*OCC_STRIDE2;
  unsigned long long o0[4], o1[4], o2[4];
  int cnt = quarterCount(D.r0a, D.r0b, v0, rb0, occ64, o0)
          + quarterCount(D.r1a, D.r1b, v1, rb1, occ64, o1)
          + quarterCount(D.r2a, D.r2b, v2, rb2, occ64, o2);
  const int total = waveSum63(cnt);
  if (total < D.thr) {                       // == (float)total/area < 0.5f, by construction
    if (t == 0) accB[D.g] = 1;
    quarterWrite(D.r0a, D.r0b, v0, rb0, occ64, o0);
    quarterWrite(D.r1a, D.r1b, v1, rb1, occ64, o1);
    quarterWrite(D.r2a, D.r2b, v2, rb2, occ64, o2);
  }
}

__global__ void __launch_bounds__(64) k_scan(int* __restrict__ wsI) {
  const int bid = blockIdx.x, t = threadIdx.x;
  if (bid >= NB) {
    // ---- histogram slice, then clock-warming spin until both scan blocks finish ----
    __shared__ unsigned int h[2*NC];
    h[t] = 0u;
    __syncthreads();
    const unsigned int* segclsW = (const unsigned int*)((const char*)wsI + (size_t)OFF_SEGCLS*4);
    const int w0 = (bid - NB) * HIST_WORDS;
    const int hb = (w0 >> 16) << 5;            // slice lies in one batch; b*32
    for (int wi = w0 + t; wi < w0 + HIST_WORDS; wi += 64) {
      const unsigned int w = segclsW[wi];
      #pragma unroll
      for (int by = 0; by < 4; ++by) {
        const int cls = (w >> (by*8)) & 0xff;
        if (cls >= 2) atomicAdd(&h[hb + cls], 1u);
      }
    }
    __syncthreads();
    const unsigned int v = h[t];
    if (v) atomicAdd((unsigned int*)&wsI[OFF_COUNTS + t], v);
    // VALU burn keeps shader clocks boosted while the 2 serial scan blocks run.
    float acc = (float)t * 1.000001f;
    while (__hip_atomic_load(&wsI[OFF_FLAG], __ATOMIC_ACQUIRE, __HIP_MEMORY_SCOPE_AGENT) < NB) {
      #pragma unroll
      for (int i = 0; i < 256; ++i) acc = fmaf(acc, 1.0000001f, 0.5f);
      asm volatile("" :: "v"(acc));            // keep burn live (rule #17)
    }
    asm volatile("" :: "v"(acc));
    return;
  }
  const int b = bid;                          // 1 wave, lockstep, barrier-free main loop
  __shared__ unsigned int occ[OCC_WORDS];     // 53.2 KB (stride 26 -> u64 cells)
  __shared__ int s_list[ND];
  for (int i = t; i < OCC_WORDS; i += 64) occ[i] = 0u;
  // areas / acc-zero (dets t and t+64)
  const int a0 = (t < ND)      ? wsI[OFF_AREA + b*ND + t]      : 0;
  const int a1 = (t + 64 < ND) ? wsI[OFF_AREA + b*ND + t + 64] : 0;
  if (t < ND)      wsI[OFF_ACC + b*ND + t] = 0;
  if (t + 64 < ND) wsI[OFF_ACC + b*ND + t + 64] = 0;
  // ordered compaction of area>0 dets into s_list (sorted-rank order preserved)
  int nact;
  {
    const bool k0 = (t < ND) && (a0 > 0);
    const unsigned long long m0 = __ballot(k0);
    if (k0) s_list[__popcll(m0 & ((1ull << t) - 1ull))] = t;
    nact = (int)__popcll(m0);
    const bool k1 = (t + 64 < ND) && (a1 > 0);
    const unsigned long long m1 = __ballot(k1);
    if (k1) s_list[nact + __popcll(m1 & ((1ull << t) - 1ull))] = t + 64;
    nact += (int)__popcll(m1);
  }
  __syncthreads();
  if (nact > 0) {
    // pre-permuted per-lane metadata: lane l holds active det l (and l+64)
    int myb0 = 0, maux0 = 0, myb1 = 0, maux1 = 0;
    if (t < nact) {
      const int g = s_list[t];
      myb0 = wsI[OFF_YB + b*ND + g];
      const int q0 = wsI[OFF_QN + b*ND + g] & 0xffff;
      const int area = wsI[OFF_AREA + b*ND + g];
      int c = (area + 1) >> 1;                  // min c with (float)c/area >= 0.5f
      const float a = (float)area;
      while (c > 0 && (float)(c - 1) / a >= 0.5f) --c;
      while ((float)c / a < 0.5f) ++c;
      maux0 = q0 | (g << 4) | (c << 11);
    }
    if (t + 64 < nact) {
      const int g = s_list[t + 64];
      myb1 = wsI[OFF_YB + b*ND + g];
      const int q0 = wsI[OFF_QN + b*ND + g] & 0xffff;
      const int area = wsI[OFF_AREA + b*ND + g];
      int c = (area + 1) >> 1;
      const float a = (float)area;
      while (c > 0 && (float)(c - 1) / a >= 0.5f) --c;
      while ((float)c / a < 0.5f) ++c;
      maux1 = q0 | (g << 4) | (c << 11);
    }
    const ulonglong2* bmp2 = (const ulonglong2*)((unsigned int*)wsI + OFF_BMP8 + (size_t)b*ND*BMP8_DETWORDS);
    unsigned long long* occ64 = (unsigned long long*)occ;
    int* accB = wsI + OFF_ACC + b*ND;
    const int last = nact - 1;
    // uniform metadata access: few-cycle readlane instead of LDS round-trips
    #define MYB(ii)  ((ii) < 64 ? __builtin_amdgcn_readlane(myb0,  (ii)) \
                                : __builtin_amdgcn_readlane(myb1,  (ii) - 64))
    #define MAUX(ii) ((ii) < 64 ? __builtin_amdgcn_readlane(maux0, (ii)) \
                                : __builtin_amdgcn_readlane(maux1, (ii) - 64))
    DetReg A, B, C, D;
    { int i0 = 0;              fetchD(MYB(i0), MAUX(i0), t, bmp2, A); }
    { int i1 = min(1, last);   fetchD(MYB(i1), MAUX(i1), t, bmp2, B); }
    { int i2 = min(2, last);   fetchD(MYB(i2), MAUX(i2), t, bmp2, C); }
    { int i3 = min(3, last);   fetchD(MYB(i3), MAUX(i3), t, bmp2, D); }
    for (int ii = 0; ii < nact; ii += 4) {
      processDet(t, A, occ64, accB);
      { const int n = min(ii + 4, last); fetchD(MYB(n), MAUX(n), t, bmp2, A); }
      if (ii + 1 < nact) processDet(t, B, occ64, accB);
      { const int n = min(ii + 5, last); fetchD(MYB(n), MAUX(n), t, bmp2, B); }
      if (ii + 2 < nact) processDet(t, C, occ64, accB);
      { const int n = min(ii + 6, last); fetchD(MYB(n), MAUX(n), t, bmp2, C); }
      if (ii + 3 < nact) processDet(t, D, occ64, accB);
      { const int n = min(ii + 7, last); fetchD(MYB(n), MAUX(n), t, bmp2, D); }
    }
    #undef MYB
    #undef MAUX
  }
  // signal done (every exit path of scan blocks)
  if (t == 0)
    __hip_atomic_fetch_add(&wsI[OFF_FLAG], 1, __ATOMIC_RELEASE, __HIP_MEMORY_SCOPE_AGENT);
}

// ================= K3: paint owners via atomicMin, 4 rows per iteration =================
__global__ void __launch_bounds__(1024) k_paint(const int* __restrict__ wsI,
                                                int* __restrict__ out) {
  const int g = blockIdx.x;             // b*ND + k
  if (!wsI[OFF_ACC + g]) return;        // uniform
  const int t = threadIdx.x;            // 1024 = 4 rows x 8 words x 32 bits
  const int b = g / ND, k = g - b*ND;
  const int yb = wsI[OFF_YB + g];
  const int ylo = yb & 0xffff;
  const int rows = (yb >> 16) - ylo;
  const int q0 = wsI[OFF_QN + g] & 0xffff;   // even-aligned base word
  const unsigned int* bmp = (const unsigned int*)wsI + OFF_BMP8 + g*BMP8_DETWORDS;
  int* __restrict__ owner = out + b*(OH*OW);     // plane 0 doubles as owner map
  const int rq = t >> 8;                // row quarter 0..3
  const int px = t & 255;
  const int iw = px >> 5, bit = px & 31;
  const int x = ((q0 + iw) << 5) + bit;
  if (x >= OW) return;                  // pad-word lanes carry zero bits
  #pragma unroll 2
  for (int r = rq; r < rows; r += 4) {
    const unsigned int wv = bmp[r*BMP8_ROWWORDS + iw];
    if ((wv >> bit) & 1u)
      atomicMin(&owner[(ylo + r)*OW + x], k);    // owner = min sorted rank == ref
  }
}

// ================= K4: resolve owner -> inst/cat, else stuff (uint4 vectorized) =================
__global__ void k_resolve(const int* __restrict__ wsI, int* __restrict__ out) {
  const int t = threadIdx.x;
  const int q = blockIdx.x*256 + t;      // quad index (4 px)
  const int b = q >> 16;
  __shared__ int s_val[ND];
  __shared__ int s_cnt[NC];
  if (t < ND) s_val[t] = wsI[OFF_VAL + b*ND + t];
  if (t >= 128 && t < 128 + NC) s_cnt[t - 128] = wsI[OFF_COUNTS + b*32 + (t - 128)];
  __syncthreads();
  const uint4 o4 = ((const uint4*)out)[q];
  const unsigned int clsw = ((const unsigned int*)((const char*)wsI + (size_t)OFF_SEGCLS*4))[q];
  uint4 i4, c4;
  {
    const int o = (int)o4.x;
    if (o < ND) { const int v = s_val[o]; i4.x = v & 0xffff; c4.x = v >> 16; }
    else { i4.x = (unsigned)-1; const int cl = clsw & 0xff;
           c4.x = (cl >= 2 && s_cnt[cl] > 4096) ? cl + 90 : 0; }
  }
  {
    const int o = (int)o4.y;
    if (o < ND) { const int v = s_val[o]; i4.y = v & 0xffff; c4.y = v >> 16; }
    else { i4.y = (unsigned)-1; const int cl = (clsw >> 8) & 0xff;
           c4.y = (cl >= 2 && s_cnt[cl] > 4096) ? cl + 90 : 0; }
  }
  {
    const int o = (int)o4.z;
    if (o < ND) { const int v = s_val[o]; i4.z = v & 0xffff; c4.z = v >> 16; }
    else { i4.z = (unsigned)-1; const int cl = (clsw >> 16) & 0xff;
           c4.z = (cl >= 2 && s_cnt[cl] > 4096) ? cl + 90 : 0; }
  }
  {
    const int o = (int)o4.w;
    if (o < ND) { const int v = s_val[o]; i4.w = v & 0xffff; c4.w = v >> 16; }
    else { i4.w = (unsigned)-1; const int cl = (clsw >> 24) & 0xff;
           c4.w = (cl >= 2 && s_cnt[cl] > 4096) ? cl + 90 : 0; }
  }
  ((uint4*)out)[q] = i4;
  ((uint4*)(out + NB*OH*OW))[q] = c4;
}

extern "C" void kernel_launch(void* const* d_in, const int* in_sizes, int n_in,
                              void* d_out, int out_size, void* d_ws, size_t ws_size,
                              hipStream_t stream) {
  const float* boxes   = (const float*)d_in[0];
  const int*   classes = (const int*)d_in[1];
  const float* scores  = (const float*)d_in[2];
  const float* dmasks  = (const float*)d_in[3];
  const float* segp    = (const float*)d_in[4];
  int* wsI = (int*)d_ws;
  int* out = (int*)d_out;

  k_segmask<<<128 + NB*ND, 1024, 0, stream>>>(boxes, classes, scores, dmasks, segp, wsI, out);
  {
    // cooperative launch: guarantees co-residency so the warming spin cannot deadlock (G16)
    void* args[] = { (void*)&wsI };
    hipLaunchCooperativeKernel((const void*)k_scan, dim3(NB + NHIST), dim3(64), args, 0, stream);
  }
  k_paint  <<<NB*ND, 1024, 0, stream>>>(wsI, out);
  k_resolve<<<(NB*OH*OW)/1024, 256, 0, stream>>>(wsI, out);
}

// Round 16
// 93.838 us; speedup vs baseline: 1.2929x; 1.2929x over previous
//
#include <hip/hip_runtime.h>

#pragma clang fp contract(off)

namespace {
constexpr int NB = 2, ND = 100, MH = 28, MW = 28;
constexpr int OH = 512, OW = 512;
constexpr int SH = 128, SW = 128, NC = 32;
constexpr int BMP_ROWS = 172;
constexpr int BMP8_ROWWORDS = 8;                        // canvas-aligned words per row (even q0)
constexpr int BMP8_DETWORDS = BMP_ROWS * BMP8_ROWWORDS; // 1376

// workspace layout (int32 word indices)
constexpr int OFF_COUNTS = 0;                     // NB*32
constexpr int OFF_AREA   = 64;                    // NB*ND
constexpr int OFF_ACC    = OFF_AREA + NB*ND;
constexpr int OFF_YB     = OFF_ACC  + NB*ND;
constexpr int OFF_VAL    = OFF_YB   + NB*ND;
constexpr int OFF_QN     = OFF_VAL  + NB*ND;
constexpr int OFF_SEGCLS = OFF_QN   + NB*ND;      // byte region: NB*OH*OW bytes
constexpr int OFF_BMP8   = OFF_SEGCLS + (NB*OH*OW)/4;
constexpr int OCC_STRIDE = 26;                    // EVEN -> 8B-aligned u64 cells; q0e+7 <= 21 < 26
constexpr int OCC_STRIDE2 = OCC_STRIDE/2;         // 13 u64 per row
constexpr int OCC_WORDS  = OH * OCC_STRIDE;       // 13312 words = 53.2 KB
constexpr int SEGW_TOTAL = (NB*OH*OW)/4;          // 131072 segcls words
constexpr int NHIST      = 128;                   // histogram blocks inside k_scan
constexpr int HIST_WORDS = SEGW_TOTAL / NHIST;    // 1024 words per hist block
static_assert(OFF_BMP8 % 4 == 0, "16B alignment");

struct SegSh  { float patch[NC*342]; };                          // 43.8 KB
struct MaskSh { float sc[ND]; float sm[MH*MW]; int det; int area; };
union  K1Sh   { SegSh seg; MaskSh mask; };
}

// ---------------- seg tile: 64x64 out px, 1024 thr (1 row x 4 col per thread) ----------------
__device__ __forceinline__ void segTile(int tid, int t, const float* __restrict__ segp,
                                        int* __restrict__ wsI, int* __restrict__ out,
                                        SegSh& S) {
  const int b  = tid >> 6;
  const int tl = tid & 63;
  const int oy = (tl >> 3) * 64, ox = (tl & 7) * 64;
  const int iy0 = (oy >> 2) - 1, ix0 = (ox >> 2) - 1;
  // stage patch: 18x18 px x 8 float4
  for (int idx = t; idx < 18*18*8; idx += 1024) {
    const int w  = idx & 7, px = idx >> 3;
    const int pr = px / 18, pc = px - pr*18;
    const int gy = min(max(iy0 + pr, 0), SH-1);
    const int gx = min(max(ix0 + pc, 0), SW-1);
    const float4 v = *(const float4*)(segp + (size_t)((b*SH + gy)*SW + gx)*NC + w*4);
    const int base = pr*19 + pc;
    S.patch[(w*4+0)*342 + base] = v.x;
    S.patch[(w*4+1)*342 + base] = v.y;
    S.patch[(w*4+2)*342 + base] = v.z;
    S.patch[(w*4+3)*342 + base] = v.w;
  }
  __syncthreads();
  const int ry = t >> 4;                 // 0..63 output row within tile
  const int cq = t & 15;                 // 0..15 col quad
  const int Y = oy + ry;
  float my = ((float)Y + 0.5f)*0.25f - 0.5f;
  float y0f = floorf(my);
  float fy = my - y0f;
  int y0 = (int)y0f, y1 = y0 + 1;
  if (y0 < 0)           { y0 = 0; y1 = 0; fy = 0.0f; }
  else if (y1 > SH - 1) { y1 = SH - 1; fy = 0.0f; }
  const float wy = 1.0f - fy;
  const int ro0 = (y0 - iy0)*19, ro1 = (y1 - iy0)*19;
  int co[4]; float fx[4], wx[4];
  {
    int clo[4], chi[4];
    #pragma unroll
    for (int v = 0; v < 4; ++v) {
      const int X = ox + cq*4 + v;
      float mx = ((float)X + 0.5f)*0.25f - 0.5f;
      float x0f = floorf(mx);
      float f = mx - x0f;
      int x0 = (int)x0f, x1 = x0 + 1;
      if (x0 < 0)           { x0 = 0; x1 = 0; f = 0.0f; }
      else if (x1 > SW - 1) { x1 = SW - 1; f = 0.0f; }
      clo[v] = x0 - ix0; chi[v] = x1 - ix0; fx[v] = f; wx[v] = 1.0f - f;
    }
    co[0] = clo[0]; co[1] = chi[0]; co[2] = clo[2]; co[3] = chi[2];
  }
  float best[4]; int bcls[4];
  #pragma unroll
  for (int v = 0; v < 4; ++v) { best[v] = -3.4e38f; bcls[v] = 0; }
  for (int ch = 0; ch < NC; ++ch) {
    const float* P = S.patch + ch*342;
    const float t0 = P[ro0 + co[0]], t1 = P[ro0 + co[1]];
    const float t2 = P[ro0 + co[2]], t3 = P[ro0 + co[3]];
    const float b0 = P[ro1 + co[0]], b1 = P[ro1 + co[1]];
    const float b2 = P[ro1 + co[2]], b3 = P[ro1 + co[3]];
    const float V0 = wy*t0 + fy*b0;      // vertical first (matches ref/XLA dim order)
    const float V1 = wy*t1 + fy*b1;
    const float V2 = wy*t2 + fy*b2;
    const float V3 = wy*t3 + fy*b3;
    const float v0 = wx[0]*V0 + fx[0]*V1;
    const float v1 = wx[1]*V0 + fx[1]*V1;
    const float v2 = wx[2]*V2 + fx[2]*V3;
    const float v3 = wx[3]*V2 + fx[3]*V3;
    if (v0 > best[0]) { best[0] = v0; bcls[0] = ch; }   // strict > = first max
    if (v1 > best[1]) { best[1] = v1; bcls[1] = ch; }
    if (v2 > best[2]) { best[2] = v2; bcls[2] = ch; }
    if (v3 > best[3]) { best[3] = v3; bcls[3] = ch; }
  }
  unsigned int* segclsW = (unsigned int*)((char*)wsI + (size_t)OFF_SEGCLS*4);
  const int X0 = ox + cq*4;
  const int pidw = (b*OH*OW + Y*OW + X0) >> 2;
  segclsW[pidw] = (unsigned)bcls[0] | ((unsigned)bcls[1]<<8)
                | ((unsigned)bcls[2]<<16) | ((unsigned)bcls[3]<<24);
  const uint4 sent = uint4{0x7FFFFFFFu,0x7FFFFFFFu,0x7FFFFFFFu,0x7FFFFFFFu};
  *(uint4*)(out + b*OH*OW + Y*OW + X0) = sent;          // owner sentinel
}

// ---------------- mask: per-det bitmap + area, 4 rows per iteration (even-aligned q0) ----------------
__device__ __forceinline__ void maskOne(int g, int t, const float* __restrict__ boxes,
                                        const int* __restrict__ classes,
                                        const float* __restrict__ scores,
                                        const float* __restrict__ dmasks,
                                        int* __restrict__ wsI, MaskSh& M) {
  const int b = g / ND, k = g - b*ND;
  if (t < ND) M.sc[t] = scores[b*ND + t];
  if (t == 0) M.area = 0;
  __syncthreads();
  if (t < ND) {
    float sn = M.sc[t];
    int r = 0;
    for (int j = 0; j < ND; ++j) {
      float sj = M.sc[j];
      r += (sj > sn) || (sj == sn && j < t);   // stable descending rank
    }
    if (r == k) M.det = t;
  }
  __syncthreads();
  const int det = M.det;
  const int cls = classes[b*ND + det];
  const float sc = M.sc[det];
  const float* bx = boxes + (size_t)(b*ND + det)*4;
  const float ymin = bx[0], xmin = bx[1], ymax = bx[2], xmax = bx[3];
  const bool keep = (sc > 0.5f) && (cls != 0);
  int ylo = (int)ceilf(ymin), yhi = (int)ceilf(ymax);
  int xlo = (int)ceilf(xmin), xhi = (int)ceilf(xmax);
  ylo = max(ylo, 0); xlo = max(xlo, 0);
  yhi = min(yhi, OH); xhi = min(xhi, OW);
  if (yhi < ylo) yhi = ylo;
  if (xhi < xlo) xhi = xlo;
  if (yhi - ylo > BMP_ROWS) yhi = ylo + BMP_ROWS;
  if (xhi - xlo > 192)      xhi = xlo + 192;
  const int yhi2 = keep ? yhi : ylo, xhi2 = keep ? xhi : xlo;
  const int rows = yhi2 - ylo, width = xhi2 - xlo;
  const int q0 = (xlo >> 5) & ~1;      // EVEN canvas word; span <= 63+192=255 bits <= 8 words
  const int nw = (width > 0) ? (((xlo - (q0 << 5)) + width + 31) >> 5) : 0;  // <= 8
  if (t == 0) {
    wsI[OFF_YB  + g] = ylo | (yhi2 << 16);
    wsI[OFF_VAL + g] = (det + 1) | (cls << 16);
    wsI[OFF_QN  + g] = q0 | (nw << 16);
  }
  if (rows > 0 && width > 0) {
    const float hs  = (ymax > ymin) ? (28.0f / (ymax - ymin)) : 0.0f;
    const float wsc = (xmax > xmin) ? (28.0f / (xmax - xmin)) : 0.0f;
    const float* mp = dmasks + (size_t)(b*ND + det)*(MH*MW);
    for (int i = t; i < MH*MW; i += 1024) M.sm[i] = mp[i];
    __syncthreads();
    unsigned int* bmp8 = (unsigned int*)wsI + OFF_BMP8 + g*BMP8_DETWORDS;
    const int rq = t >> 8;               // row quarter 0..3 (wave-uniform)
    const int px = t & 255;
    const int iw = px >> 5, bit = px & 31;
    const int x = ((q0 + iw) << 5) + bit;
    const bool inbox = (x >= xlo) && (x < xhi2);
    for (int r = rq; r < rows; r += 4) {
      const int y = ylo + r;
      bool pred = false;
      if (inbox) {
        // exact op order of _paste_one (fp contract off)
        float ty = ((float)y + 0.5f); ty = ty - ymin; ty = ty * hs;  float my = ty - 0.5f;
        float tx = ((float)x + 0.5f); tx = tx - xmin; tx = tx * wsc; float mx = tx - 0.5f;
        float y0f = floorf(my), x0f = floorf(mx);
        float ly = my - y0f, lx = mx - x0f;
        int y0 = (int)y0f, x0 = (int)x0f;
        int y1 = min(max(y0 + 1, 0), MH - 1);
        int x1 = min(max(x0 + 1, 0), MW - 1);
        y0 = min(max(y0, 0), MH - 1);
        x0 = min(max(x0, 0), MW - 1);
        float v00 = M.sm[y0*MW + x0], v01 = M.sm[y0*MW + x1];
        float v10 = M.sm[y1*MW + x0], v11 = M.sm[y1*MW + x1];
        float omlx = 1.0f - lx, omly = 1.0f - ly;
        float top = omlx*v00 + lx*v01;
        float bot = omlx*v10 + lx*v11;
        float outv = omly*top + ly*bot;
        pred = outv > 0.5f;
      }
      unsigned long long m = __ballot(pred);
      unsigned int word = (px & 32) ? (unsigned int)(m >> 32) : (unsigned int)m;
      if (bit == 0) {
        bmp8[r*BMP8_ROWWORDS + iw] = word;
        if (word) atomicAdd(&M.area, __popc(word));
      }
    }
  }
  __syncthreads();
  if (t == 0) wsI[OFF_AREA + g] = (rows > 0 && width > 0) ? M.area : 0;
}

// ================= K1: tiled seg (blocks 0..127) + masks (blocks 128..327) =================
__global__ void __launch_bounds__(1024) k_segmask(
    const float* __restrict__ boxes, const int* __restrict__ classes,
    const float* __restrict__ scores, const float* __restrict__ dmasks,
    const float* __restrict__ segp, int* __restrict__ wsI, int* __restrict__ out) {
  __shared__ K1Sh sh;
  const int bid = blockIdx.x, t = threadIdx.x;
  if (bid == 0 && t < 2*NC) wsI[OFF_COUNTS + t] = 0;   // zero class counters (used next kernel)
  if (bid < 128) segTile(bid, t, segp, wsI, out, sh.seg);
  else           maskOne(bid - 128, t, boxes, classes, scores, dmasks, wsI, sh.mask);
}

// ================= K2: scan (blocks 0..1, u64 occ, ds_or) + histogram (2..129) =================
namespace {
struct DetReg {
  int g, q2, yb, thr;
  unsigned free;
  ulonglong2 r0a, r0b, r1a, r1b, r2a, r2b;   // per row-quarter: a=words0-3, b=words4-7
};
}

// aux packing: q0e[0:3] | nw[4:7] | g[8:14] | thr[15:29] | free[30]
__device__ __forceinline__ void fetchD(int yb, int aux, int t,
                                       const ulonglong2* __restrict__ bmp2, DetReg& D) {
  D.yb   = yb;
  D.q2   = (aux & 15) >> 1;
  D.g    = (aux >> 8) & 127;
  D.thr  = (aux >> 15) & 0x7fff;
  D.free = ((unsigned)aux >> 30) & 1u;
  const int rows = (yb >> 16) - (yb & 0xffff);
  const ulonglong2* p = bmp2 + (size_t)D.g*(BMP8_DETWORDS/4);
  const ulonglong2 z = ulonglong2{0ull, 0ull};
  D.r0a = z; D.r0b = z; D.r1a = z; D.r1b = z; D.r2a = z; D.r2b = z;
  if (t < rows)       { D.r0a = p[t*2];         D.r0b = p[t*2 + 1]; }
  if (t + 64 < rows)  { D.r1a = p[(t+64)*2];    D.r1b = p[(t+64)*2 + 1]; }
  if (t + 128 < rows) { D.r2a = p[(t+128)*2];   D.r2b = p[(t+128)*2 + 1]; }
}

__device__ __forceinline__ int waveSum63(int cnt) {
  // 64-lane sum via DPP (row_shr 1/2/4/8 + row_bcast15/31); total lands in lane 63
  cnt += __builtin_amdgcn_update_dpp(0, cnt, 0x111, 0xF, 0xF, false);
  cnt += __builtin_amdgcn_update_dpp(0, cnt, 0x112, 0xF, 0xF, false);
  cnt += __builtin_amdgcn_update_dpp(0, cnt, 0x114, 0xF, 0xF, false);
  cnt += __builtin_amdgcn_update_dpp(0, cnt, 0x118, 0xF, 0xF, false);
  cnt += __builtin_amdgcn_update_dpp(0, cnt, 0x142, 0xF, 0xF, false);
  cnt += __builtin_amdgcn_update_dpp(0, cnt, 0x143, 0xF, 0xF, false);
  return __builtin_amdgcn_readlane(cnt, 63);
}

__device__ __forceinline__ void processDet(int t, const DetReg& D,
                                           unsigned long long* occ64,
                                           int* __restrict__ accB) {
  const int ylo = D.yb & 0xffff;
  const int rows = (D.yb >> 16) - ylo;
  const bool v0 = t < rows, v1 = t + 64 < rows, v2 = t + 128 < rows;
  const int rb0 = (ylo + t) * OCC_STRIDE2 + D.q2;
  const int rb1 = rb0 + 64*OCC_STRIDE2;
  const int rb2 = rb0 + 128*OCC_STRIDE2;
  bool acc = true;
  if (!D.free) {                         // wave-uniform branch
    int cnt = 0;
    if (v0) {
      cnt += __popcll(D.r0a.x & occ64[rb0+0]); cnt += __popcll(D.r0a.y & occ64[rb0+1]);
      cnt += __popcll(D.r0b.x & occ64[rb0+2]); cnt += __popcll(D.r0b.y & occ64[rb0+3]);
    }
    if (v1) {
      cnt += __popcll(D.r1a.x & occ64[rb1+0]); cnt += __popcll(D.r1a.y & occ64[rb1+1]);
      cnt += __popcll(D.r1b.x & occ64[rb1+2]); cnt += __popcll(D.r1b.y & occ64[rb1+3]);
    }
    if (v2) {
      cnt += __popcll(D.r2a.x & occ64[rb2+0]); cnt += __popcll(D.r2a.y & occ64[rb2+1]);
      cnt += __popcll(D.r2b.x & occ64[rb2+2]); cnt += __popcll(D.r2b.y & occ64[rb2+3]);
    }
    acc = waveSum63(cnt) < D.thr;        // == (float)total/area < 0.5f, by construction
  }
  if (acc) {
    if (t == 0) accB[D.g] = 1;
    // value-independent ORs: no lgkm drain between dets (DS pipe is in-order per wave)
    if (v0) {
      atomicOr(&occ64[rb0+0], D.r0a.x); atomicOr(&occ64[rb0+1], D.r0a.y);
      atomicOr(&occ64[rb0+2], D.r0b.x); atomicOr(&occ64[rb0+3], D.r0b.y);
    }
    if (v1) {
      atomicOr(&occ64[rb1+0], D.r1a.x); atomicOr(&occ64[rb1+1], D.r1a.y);
      atomicOr(&occ64[rb1+2], D.r1b.x); atomicOr(&occ64[rb1+3], D.r1b.y);
    }
    if (v2) {
      atomicOr(&occ64[rb2+0], D.r2a.x); atomicOr(&occ64[rb2+1], D.r2a.y);
      atomicOr(&occ64[rb2+2], D.r2b.x); atomicOr(&occ64[rb2+3], D.r2b.y);
    }
  }
}

__global__ void __launch_bounds__(64) k_scan(int* __restrict__ wsI) {
  const int bid = blockIdx.x, t = threadIdx.x;
  if (bid >= NB) {
    // ---- histogram slice (runs alongside the serial scan) ----
    __shared__ unsigned int h[2*NC];
    h[t] = 0u;
    __syncthreads();
    const unsigned int* segclsW = (const unsigned int*)((const char*)wsI + (size_t)OFF_SEGCLS*4);
    const int w0 = (bid - NB) * HIST_WORDS;
    const int hb = (w0 >> 16) << 5;            // slice lies in one batch; b*32
    for (int wi = w0 + t; wi < w0 + HIST_WORDS; wi += 64) {
      const unsigned int w = segclsW[wi];
      #pragma unroll
      for (int by = 0; by < 4; ++by) {
        const int cls = (w >> (by*8)) & 0xff;
        if (cls >= 2) atomicAdd(&h[hb + cls], 1u);
      }
    }
    __syncthreads();
    const unsigned int v = h[t];
    if (v) atomicAdd((unsigned int*)&wsI[OFF_COUNTS + t], v);
    return;
  }
  const int b = bid;                          // 1 wave, lockstep, barrier-free main loop
  __shared__ unsigned int occ[OCC_WORDS];     // 53.2 KB (stride 26 -> u64 cells)
  __shared__ int s_list[ND];
  for (int i = t; i < OCC_WORDS; i += 64) occ[i] = 0u;
  const int a0 = (t < ND)      ? wsI[OFF_AREA + b*ND + t]      : 0;
  const int a1 = (t + 64 < ND) ? wsI[OFF_AREA + b*ND + t + 64] : 0;
  if (t < ND)      wsI[OFF_ACC + b*ND + t] = 0;
  if (t + 64 < ND) wsI[OFF_ACC + b*ND + t + 64] = 0;
  // ordered compaction of area>0 dets into s_list (sorted-rank order preserved)
  int nact;
  {
    const bool k0 = (t < ND) && (a0 > 0);
    const unsigned long long m0 = __ballot(k0);
    if (k0) s_list[__popcll(m0 & ((1ull << t) - 1ull))] = t;
    nact = (int)__popcll(m0);
    const bool k1 = (t + 64 < ND) && (a1 > 0);
    const unsigned long long m1 = __ballot(k1);
    if (k1) s_list[nact + __popcll(m1 & ((1ull << t) - 1ull))] = t + 64;
    nact += (int)__popcll(m1);
  }
  __syncthreads();
  if (nact == 0) return;
  // pre-permuted per-lane metadata: lane l holds active det l (and l+64)
  int myb0 = 0, maux0 = 0, myb1 = 0, maux1 = 0;
  if (t < nact) {
    const int g = s_list[t];
    myb0 = wsI[OFF_YB + b*ND + g];
    const int qn = wsI[OFF_QN + b*ND + g];
    const int q0 = qn & 0xffff, nw = qn >> 16;
    const int area = wsI[OFF_AREA + b*ND + g];
    int c = (area + 1) >> 1;                  // min c with (float)c/area >= 0.5f
    const float a = (float)area;
    while (c > 0 && (float)(c - 1) / a >= 0.5f) --c;
    while ((float)c / a < 0.5f) ++c;
    maux0 = q0 | (nw << 4) | (g << 8) | (c << 15);
  }
  if (t + 64 < nact) {
    const int g = s_list[t + 64];
    myb1 = wsI[OFF_YB + b*ND + g];
    const int qn = wsI[OFF_QN + b*ND + g];
    const int q0 = qn & 0xffff, nw = qn >> 16;
    const int area = wsI[OFF_AREA + b*ND + g];
    int c = (area + 1) >> 1;
    const float a = (float)area;
    while (c > 0 && (float)(c - 1) / a >= 0.5f) --c;
    while ((float)c / a < 0.5f) ++c;
    maux1 = q0 | (nw << 4) | (g << 8) | (c << 15);
  }
  // uniform metadata access macros
  #define MYB(ii)  ((ii) < 64 ? __builtin_amdgcn_readlane(myb0,  (ii)) \
                              : __builtin_amdgcn_readlane(myb1,  (ii) - 64))
  #define MAUX(ii) ((ii) < 64 ? __builtin_amdgcn_readlane(maux0, (ii)) \
                              : __builtin_amdgcn_readlane(maux1, (ii) - 64))
  // free-accept: det free iff NO earlier active det's (conservative word-granular) bbox
  // intersects it -> occ&bm == 0 -> frac 0 < 0.5 -> accept without counting.
  {
    const int ylo0 = myb0 & 0xffff, yhi0 = myb0 >> 16;
    const int q00 = maux0 & 15, nw0 = (maux0 >> 4) & 15;
    const int ylo1 = myb1 & 0xffff, yhi1 = myb1 >> 16;
    const int q01 = maux1 & 15, nw1 = (maux1 >> 4) & 15;
    unsigned fr0 = 1u, fr1 = 1u;
    for (int j = 0; j < nact; ++j) {          // uniform loop
      const int jyb = MYB(j), jaux = MAUX(j);
      const int jylo = jyb & 0xffff, jyhi = jyb >> 16;
      const int jq = jaux & 15, jnw = (jaux >> 4) & 15;
      if (j < t) {
        const bool ov = (jylo < yhi0) && (ylo0 < jyhi) &&
                        (jq < q00 + nw0) && (q00 < jq + jnw);
        if (ov) fr0 = 0u;
      }
      if (j < t + 64) {
        const bool ov = (jylo < yhi1) && (ylo1 < jyhi) &&
                        (jq < q01 + nw1) && (q01 < jq + jnw);
        if (ov) fr1 = 0u;
      }
    }
    maux0 |= (int)(fr0 << 30);
    maux1 |= (int)(fr1 << 30);
  }
  const ulonglong2* bmp2 = (const ulonglong2*)((unsigned int*)wsI + OFF_BMP8 + (size_t)b*ND*BMP8_DETWORDS);
  unsigned long long* occ64 = (unsigned long long*)occ;
  int* accB = wsI + OFF_ACC + b*ND;
  const int last = nact - 1;
  DetReg A, B, C, D;
  { int i0 = 0;              fetchD(MYB(i0), MAUX(i0), t, bmp2, A); }
  { int i1 = min(1, last);   fetchD(MYB(i1), MAUX(i1), t, bmp2, B); }
  { int i2 = min(2, last);   fetchD(MYB(i2), MAUX(i2), t, bmp2, C); }
  { int i3 = min(3, last);   fetchD(MYB(i3), MAUX(i3), t, bmp2, D); }
  for (int ii = 0; ii < nact; ii += 4) {
    processDet(t, A, occ64, accB);
    { const int n = min(ii + 4, last); fetchD(MYB(n), MAUX(n), t, bmp2, A); }
    if (ii + 1 < nact) processDet(t, B, occ64, accB);
    { const int n = min(ii + 5, last); fetchD(MYB(n), MAUX(n), t, bmp2, B); }
    if (ii + 2 < nact) processDet(t, C, occ64, accB);
    { const int n = min(ii + 6, last); fetchD(MYB(n), MAUX(n), t, bmp2, C); }
    if (ii + 3 < nact) processDet(t, D, occ64, accB);
    { const int n = min(ii + 7, last); fetchD(MYB(n), MAUX(n), t, bmp2, D); }
  }
  #undef MYB
  #undef MAUX
}

// ================= K3: paint owners via atomicMin, 4 rows per iteration =================
__global__ void __launch_bounds__(1024) k_paint(const int* __restrict__ wsI,
                                                int* __restrict__ out) {
  const int g = blockIdx.x;             // b*ND + k
  if (!wsI[OFF_ACC + g]) return;        // uniform
  const int t = threadIdx.x;            // 1024 = 4 rows x 8 words x 32 bits
  const int b = g / ND, k = g - b*ND;
  const int yb = wsI[OFF_YB + g];
  const int ylo = yb & 0xffff;
  const int rows = (yb >> 16) - ylo;
  const int q0 = wsI[OFF_QN + g] & 0xffff;   // even-aligned base word
  const unsigned int* bmp = (const unsigned int*)wsI + OFF_BMP8 + g*BMP8_DETWORDS;
  int* __restrict__ owner = out + b*(OH*OW);     // plane 0 doubles as owner map
  const int rq = t >> 8;                // row quarter 0..3
  const int px = t & 255;
  const int iw = px >> 5, bit = px & 31;
  const int x = ((q0 + iw) << 5) + bit;
  if (x >= OW) return;                  // pad-word lanes carry zero bits
  #pragma unroll 2
  for (int r = rq; r < rows; r += 4) {
    const unsigned int wv = bmp[r*BMP8_ROWWORDS + iw];
    if ((wv >> bit) & 1u)
      atomicMin(&owner[(ylo + r)*OW + x], k);    // owner = min sorted rank == ref
  }
}

// ================= K4: resolve owner -> inst/cat, else stuff (uint4 vectorized) =================
__global__ void k_resolve(const int* __restrict__ wsI, int* __restrict__ out) {
  const int t = threadIdx.x;
  const int q = blockIdx.x*256 + t;      // quad index (4 px)
  const int b = q >> 16;
  __shared__ int s_val[ND];
  __shared__ int s_cnt[NC];
  if (t < ND) s_val[t] = wsI[OFF_VAL + b*ND + t];
  if (t >= 128 && t < 128 + NC) s_cnt[t - 128] = wsI[OFF_COUNTS + b*32 + (t - 128)];
  __syncthreads();
  const uint4 o4 = ((const uint4*)out)[q];
  const unsigned int clsw = ((const unsigned int*)((const char*)wsI + (size_t)OFF_SEGCLS*4))[q];
  uint4 i4, c4;
  {
    const int o = (int)o4.x;
    if (o < ND) { const int v = s_val[o]; i4.x = v & 0xffff; c4.x = v >> 16; }
    else { i4.x = (unsigned)-1; const int cl = clsw & 0xff;
           c4.x = (cl >= 2 && s_cnt[cl] > 4096) ? cl + 90 : 0; }
  }
  {
    const int o = (int)o4.y;
    if (o < ND) { const int v = s_val[o]; i4.y = v & 0xffff; c4.y = v >> 16; }
    else { i4.y = (unsigned)-1; const int cl = (clsw >> 8) & 0xff;
           c4.y = (cl >= 2 && s_cnt[cl] > 4096) ? cl + 90 : 0; }
  }
  {
    const int o = (int)o4.z;
    if (o < ND) { const int v = s_val[o]; i4.z = v & 0xffff; c4.z = v >> 16; }
    else { i4.z = (unsigned)-1; const int cl = (clsw >> 16) & 0xff;
           c4.z = (cl >= 2 && s_cnt[cl] > 4096) ? cl + 90 : 0; }
  }
  {
    const int o = (int)o4.w;
    if (o < ND) { const int v = s_val[o]; i4.w = v & 0xffff; c4.w = v >> 16; }
    else { i4.w = (unsigned)-1; const int cl = (clsw >> 24) & 0xff;
           c4.w = (cl >= 2 && s_cnt[cl] > 4096) ? cl + 90 : 0; }
  }
  ((uint4*)out)[q] = i4;
  ((uint4*)(out + NB*OH*OW))[q] = c4;
}

extern "C" void kernel_launch(void* const* d_in, const int* in_sizes, int n_in,
                              void* d_out, int out_size, void* d_ws, size_t ws_size,
                              hipStream_t stream) {
  const float* boxes   = (const float*)d_in[0];
  const int*   classes = (const int*)d_in[1];
  const float* scores  = (const float*)d_in[2];
  const float* dmasks  = (const float*)d_in[3];
  const float* segp    = (const float*)d_in[4];
  int* wsI = (int*)d_ws;
  int* out = (int*)d_out;

  k_segmask<<<128 + NB*ND, 1024, 0, stream>>>(boxes, classes, scores, dmasks, segp, wsI, out);
  k_scan   <<<NB + NHIST, 64, 0, stream>>>(wsI);
  k_paint  <<<NB*ND, 1024, 0, stream>>>(wsI, out);
  k_resolve<<<(NB*OH*OW)/1024, 256, 0, stream>>>(wsI, out);
}

// Round 17
// 85.260 us; speedup vs baseline: 1.4230x; 1.1006x over previous
//
#include <hip/hip_runtime.h>

#pragma clang fp contract(off)

namespace {
constexpr int NB = 2, ND = 100, MH = 28, MW = 28;
constexpr int OH = 512, OW = 512;
constexpr int SH = 128, SW = 128, NC = 32;
constexpr int BMP_ROWS = 172;
constexpr int BMP8_ROWWORDS = 8;                        // canvas-aligned words per row (even q0)
constexpr int BMP8_DETWORDS = BMP_ROWS * BMP8_ROWWORDS; // 1376

// workspace layout (int32 word indices)
constexpr int OFF_COUNTS = 0;                     // NB*32
constexpr int OFF_AREA   = 64;                    // NB*ND
constexpr int OFF_ACC    = OFF_AREA + NB*ND;
constexpr int OFF_YB     = OFF_ACC  + NB*ND;
constexpr int OFF_VAL    = OFF_YB   + NB*ND;
constexpr int OFF_QN     = OFF_VAL  + NB*ND;
constexpr int OFF_SEGCLS = OFF_QN   + NB*ND;      // byte region: NB*OH*OW bytes
constexpr int OFF_BMP8   = OFF_SEGCLS + (NB*OH*OW)/4;
constexpr int OCC_STRIDE = 26;                    // EVEN -> 8B-aligned u64 cells; q0e+7 <= 21 < 26
constexpr int OCC_STRIDE2 = OCC_STRIDE/2;         // 13 u64 per row (odd -> 2-way conflict = free)
constexpr int OCC_WORDS  = OH * OCC_STRIDE;       // 13312 words = 53.2 KB
constexpr int SEGW_TOTAL = (NB*OH*OW)/4;          // 131072 segcls words
constexpr int NHIST      = 128;                   // histogram blocks inside k_scan
constexpr int HIST_WORDS = SEGW_TOTAL / NHIST;    // 1024 words per hist block
static_assert(OFF_BMP8 % 4 == 0, "16B alignment");

struct SegSh  { float patch[NC*342]; };                          // 43.8 KB
struct MaskSh { float sc[ND]; float sm[MH*MW]; int det; int area; };
union  K1Sh   { SegSh seg; MaskSh mask; };
}

// ---------------- seg tile: 64x64 out px, 1024 thr (1 row x 4 col per thread) ----------------
__device__ __forceinline__ void segTile(int tid, int t, const float* __restrict__ segp,
                                        int* __restrict__ wsI, int* __restrict__ out,
                                        SegSh& S) {
  const int b  = tid >> 6;
  const int tl = tid & 63;
  const int oy = (tl >> 3) * 64, ox = (tl & 7) * 64;
  const int iy0 = (oy >> 2) - 1, ix0 = (ox >> 2) - 1;
  // stage patch: 18x18 px x 8 float4
  for (int idx = t; idx < 18*18*8; idx += 1024) {
    const int w  = idx & 7, px = idx >> 3;
    const int pr = px / 18, pc = px - pr*18;
    const int gy = min(max(iy0 + pr, 0), SH-1);
    const int gx = min(max(ix0 + pc, 0), SW-1);
    const float4 v = *(const float4*)(segp + (size_t)((b*SH + gy)*SW + gx)*NC + w*4);
    const int base = pr*19 + pc;
    S.patch[(w*4+0)*342 + base] = v.x;
    S.patch[(w*4+1)*342 + base] = v.y;
    S.patch[(w*4+2)*342 + base] = v.z;
    S.patch[(w*4+3)*342 + base] = v.w;
  }
  __syncthreads();
  const int ry = t >> 4;                 // 0..63 output row within tile
  const int cq = t & 15;                 // 0..15 col quad
  const int Y = oy + ry;
  // y table (weights exact eighths; clamp -> f=0 single-tap exact)
  float my = ((float)Y + 0.5f)*0.25f - 0.5f;
  float y0f = floorf(my);
  float fy = my - y0f;
  int y0 = (int)y0f, y1 = y0 + 1;
  if (y0 < 0)           { y0 = 0; y1 = 0; fy = 0.0f; }
  else if (y1 > SH - 1) { y1 = SH - 1; fy = 0.0f; }
  const float wy = 1.0f - fy;
  const int ro0 = (y0 - iy0)*19, ro1 = (y1 - iy0)*19;
  // col tables; v01 share x0/x1, v23 share (holds under edge clamps too)
  int co[4]; float fx[4], wx[4];
  {
    int clo[4], chi[4];
    #pragma unroll
    for (int v = 0; v < 4; ++v) {
      const int X = ox + cq*4 + v;
      float mx = ((float)X + 0.5f)*0.25f - 0.5f;
      float x0f = floorf(mx);
      float f = mx - x0f;
      int x0 = (int)x0f, x1 = x0 + 1;
      if (x0 < 0)           { x0 = 0; x1 = 0; f = 0.0f; }
      else if (x1 > SW - 1) { x1 = SW - 1; f = 0.0f; }
      clo[v] = x0 - ix0; chi[v] = x1 - ix0; fx[v] = f; wx[v] = 1.0f - f;
    }
    co[0] = clo[0]; co[1] = chi[0]; co[2] = clo[2]; co[3] = chi[2];
  }
  float best[4]; int bcls[4];
  #pragma unroll
  for (int v = 0; v < 4; ++v) { best[v] = -3.4e38f; bcls[v] = 0; }
  for (int ch = 0; ch < NC; ++ch) {
    const float* P = S.patch + ch*342;
    const float t0 = P[ro0 + co[0]], t1 = P[ro0 + co[1]];
    const float t2 = P[ro0 + co[2]], t3 = P[ro0 + co[3]];
    const float b0 = P[ro1 + co[0]], b1 = P[ro1 + co[1]];
    const float b2 = P[ro1 + co[2]], b3 = P[ro1 + co[3]];
    const float V0 = wy*t0 + fy*b0;      // vertical first (matches ref/XLA dim order)
    const float V1 = wy*t1 + fy*b1;
    const float V2 = wy*t2 + fy*b2;
    const float V3 = wy*t3 + fy*b3;
    const float v0 = wx[0]*V0 + fx[0]*V1;
    const float v1 = wx[1]*V0 + fx[1]*V1;
    const float v2 = wx[2]*V2 + fx[2]*V3;
    const float v3 = wx[3]*V2 + fx[3]*V3;
    if (v0 > best[0]) { best[0] = v0; bcls[0] = ch; }   // strict > = first max
    if (v1 > best[1]) { best[1] = v1; bcls[1] = ch; }
    if (v2 > best[2]) { best[2] = v2; bcls[2] = ch; }
    if (v3 > best[3]) { best[3] = v3; bcls[3] = ch; }
  }
  unsigned int* segclsW = (unsigned int*)((char*)wsI + (size_t)OFF_SEGCLS*4);
  const int X0 = ox + cq*4;
  const int pidw = (b*OH*OW + Y*OW + X0) >> 2;
  segclsW[pidw] = (unsigned)bcls[0] | ((unsigned)bcls[1]<<8)
                | ((unsigned)bcls[2]<<16) | ((unsigned)bcls[3]<<24);
  const uint4 sent = uint4{0x7FFFFFFFu,0x7FFFFFFFu,0x7FFFFFFFu,0x7FFFFFFFu};
  *(uint4*)(out + b*OH*OW + Y*OW + X0) = sent;          // owner sentinel
}

// ---------------- mask: per-det bitmap + area, 4 rows per iteration (even-aligned q0) ----------------
__device__ __forceinline__ void maskOne(int g, int t, const float* __restrict__ boxes,
                                        const int* __restrict__ classes,
                                        const float* __restrict__ scores,
                                        const float* __restrict__ dmasks,
                                        int* __restrict__ wsI, MaskSh& M) {
  const int b = g / ND, k = g - b*ND;
  if (t < ND) M.sc[t] = scores[b*ND + t];
  if (t == 0) M.area = 0;
  __syncthreads();
  if (t < ND) {
    float sn = M.sc[t];
    int r = 0;
    for (int j = 0; j < ND; ++j) {
      float sj = M.sc[j];
      r += (sj > sn) || (sj == sn && j < t);   // stable descending rank
    }
    if (r == k) M.det = t;
  }
  __syncthreads();
  const int det = M.det;
  const int cls = classes[b*ND + det];
  const float sc = M.sc[det];
  const float* bx = boxes + (size_t)(b*ND + det)*4;
  const float ymin = bx[0], xmin = bx[1], ymax = bx[2], xmax = bx[3];
  const bool keep = (sc > 0.5f) && (cls != 0);
  int ylo = (int)ceilf(ymin), yhi = (int)ceilf(ymax);
  int xlo = (int)ceilf(xmin), xhi = (int)ceilf(xmax);
  ylo = max(ylo, 0); xlo = max(xlo, 0);
  yhi = min(yhi, OH); xhi = min(xhi, OW);
  if (yhi < ylo) yhi = ylo;
  if (xhi < xlo) xhi = xlo;
  if (yhi - ylo > BMP_ROWS) yhi = ylo + BMP_ROWS;
  if (xhi - xlo > 192)      xhi = xlo + 192;
  const int yhi2 = keep ? yhi : ylo, xhi2 = keep ? xhi : xlo;
  const int rows = yhi2 - ylo, width = xhi2 - xlo;
  const int q0 = (xlo >> 5) & ~1;      // EVEN canvas word; span <= 63+192=255 bits <= 8 words
  const int nw = (width > 0) ? (((xlo - (q0 << 5)) + width + 31) >> 5) : 0;  // <= 8
  if (t == 0) {
    wsI[OFF_YB  + g] = ylo | (yhi2 << 16);
    wsI[OFF_VAL + g] = (det + 1) | (cls << 16);
    wsI[OFF_QN  + g] = q0 | (nw << 16);
  }
  if (rows > 0 && width > 0) {
    const float hs  = (ymax > ymin) ? (28.0f / (ymax - ymin)) : 0.0f;
    const float wsc = (xmax > xmin) ? (28.0f / (xmax - xmin)) : 0.0f;
    const float* mp = dmasks + (size_t)(b*ND + det)*(MH*MW);
    for (int i = t; i < MH*MW; i += 1024) M.sm[i] = mp[i];
    __syncthreads();
    unsigned int* bmp8 = (unsigned int*)wsI + OFF_BMP8 + g*BMP8_DETWORDS;
    const int rq = t >> 8;               // row quarter 0..3 (wave-uniform)
    const int px = t & 255;
    const int iw = px >> 5, bit = px & 31;
    const int x = ((q0 + iw) << 5) + bit;
    const bool inbox = (x >= xlo) && (x < xhi2);
    for (int r = rq; r < rows; r += 4) {
      const int y = ylo + r;
      bool pred = false;
      if (inbox) {
        // exact op order of _paste_one (fp contract off)
        float ty = ((float)y + 0.5f); ty = ty - ymin; ty = ty * hs;  float my = ty - 0.5f;
        float tx = ((float)x + 0.5f); tx = tx - xmin; tx = tx * wsc; float mx = tx - 0.5f;
        float y0f = floorf(my), x0f = floorf(mx);
        float ly = my - y0f, lx = mx - x0f;
        int y0 = (int)y0f, x0 = (int)x0f;
        int y1 = min(max(y0 + 1, 0), MH - 1);
        int x1 = min(max(x0 + 1, 0), MW - 1);
        y0 = min(max(y0, 0), MH - 1);
        x0 = min(max(x0, 0), MW - 1);
        float v00 = M.sm[y0*MW + x0], v01 = M.sm[y0*MW + x1];
        float v10 = M.sm[y1*MW + x0], v11 = M.sm[y1*MW + x1];
        float omlx = 1.0f - lx, omly = 1.0f - ly;
        float top = omlx*v00 + lx*v01;
        float bot = omlx*v10 + lx*v11;
        float outv = omly*top + ly*bot;
        pred = outv > 0.5f;
      }
      unsigned long long m = __ballot(pred);
      unsigned int word = (px & 32) ? (unsigned int)(m >> 32) : (unsigned int)m;
      if (bit == 0) {
        bmp8[r*BMP8_ROWWORDS + iw] = word;
        if (word) atomicAdd(&M.area, __popc(word));
      }
    }
  }
  __syncthreads();
  if (t == 0) wsI[OFF_AREA + g] = (rows > 0 && width > 0) ? M.area : 0;
}

// ================= K1: tiled seg (blocks 0..127) + masks (blocks 128..327) =================
__global__ void __launch_bounds__(1024) k_segmask(
    const float* __restrict__ boxes, const int* __restrict__ classes,
    const float* __restrict__ scores, const float* __restrict__ dmasks,
    const float* __restrict__ segp, int* __restrict__ wsI, int* __restrict__ out) {
  __shared__ K1Sh sh;
  const int bid = blockIdx.x, t = threadIdx.x;
  if (bid == 0 && t < 2*NC) wsI[OFF_COUNTS + t] = 0;   // zero class counters (used next kernel)
  if (bid < 128) segTile(bid, t, segp, wsI, out, sh.seg);
  else           maskOne(bid - 128, t, boxes, classes, scores, dmasks, wsI, sh.mask);
}

// ================= K2: scan (blocks 0..1, u64 occ) + stuff histogram (blocks 2..129) =================
namespace {
struct DetReg {
  int g, q2, yb, thr;
  ulonglong2 r0a, r0b, r1a, r1b, r2a, r2b;   // per row-quarter: a=words0-3, b=words4-7
};
}

__device__ __forceinline__ void fetchD(int yb, int aux, int t,
                                       const ulonglong2* __restrict__ bmp2, DetReg& D) {
  D.yb  = yb;
  const int q0e = aux & 15;
  D.q2  = q0e >> 1;
  D.g   = (aux >> 4) & 127;
  D.thr = aux >> 11;
  const int rows = (yb >> 16) - (yb & 0xffff);
  const ulonglong2* p = bmp2 + (size_t)D.g*(BMP8_DETWORDS/4);
  const ulonglong2 z = ulonglong2{0ull, 0ull};
  D.r0a = z; D.r0b = z; D.r1a = z; D.r1b = z; D.r2a = z; D.r2b = z;
  if (t < rows)       { D.r0a = p[t*2];         D.r0b = p[t*2 + 1]; }
  if (t + 64 < rows)  { D.r1a = p[(t+64)*2];    D.r1b = p[(t+64)*2 + 1]; }
  if (t + 128 < rows) { D.r2a = p[(t+128)*2];   D.r2b = p[(t+128)*2 + 1]; }
}

__device__ __forceinline__ int quarterCount(const ulonglong2& a, const ulonglong2& b,
                                            bool valid, int rb2,
                                            const unsigned long long* occ64,
                                            unsigned long long o[4]) {
  int c = 0;
  if (valid) {
    o[0] = occ64[rb2+0]; o[1] = occ64[rb2+1]; o[2] = occ64[rb2+2]; o[3] = occ64[rb2+3];
    c += __popcll(a.x & o[0]); c += __popcll(a.y & o[1]);
    c += __popcll(b.x & o[2]); c += __popcll(b.y & o[3]);
  }
  return c;
}

__device__ __forceinline__ void quarterWrite(const ulonglong2& a, const ulonglong2& b,
                                             bool valid, int rb2,
                                             unsigned long long* occ64,
                                             const unsigned long long o[4]) {
  if (valid) {
    occ64[rb2+0] = o[0] | a.x; occ64[rb2+1] = o[1] | a.y;
    occ64[rb2+2] = o[2] | b.x; occ64[rb2+3] = o[3] | b.y;
  }
}

__device__ __forceinline__ int waveSum63(int cnt) {
  // 64-lane sum via DPP (row_shr 1/2/4/8 + row_bcast15/31); total lands in lane 63
  cnt += __builtin_amdgcn_update_dpp(0, cnt, 0x111, 0xF, 0xF, false);
  cnt += __builtin_amdgcn_update_dpp(0, cnt, 0x112, 0xF, 0xF, false);
  cnt += __builtin_amdgcn_update_dpp(0, cnt, 0x114, 0xF, 0xF, false);
  cnt += __builtin_amdgcn_update_dpp(0, cnt, 0x118, 0xF, 0xF, false);
  cnt += __builtin_amdgcn_update_dpp(0, cnt, 0x142, 0xF, 0xF, false);
  cnt += __builtin_amdgcn_update_dpp(0, cnt, 0x143, 0xF, 0xF, false);
  return __builtin_amdgcn_readlane(cnt, 63);
}

__device__ __forceinline__ void processDet(int t, const DetReg& D,
                                           unsigned long long* occ64,
                                           int* __restrict__ accB) {
  const int ylo = D.yb & 0xffff;
  const int rows = (D.yb >> 16) - ylo;
  const bool v0 = t < rows, v1 = t + 64 < rows, v2 = t + 128 < rows;
  const int rb0 = (ylo + t) * OCC_STRIDE2 + D.q2;
  const int rb1 = rb0 + 64*OCC_STRIDE2;
  const int rb2 = rb0 + 128*OCC_STRIDE2;
  unsigned long long o0[4], o1[4], o2[4];
  int cnt = quarterCount(D.r0a, D.r0b, v0, rb0, occ64, o0)
          + quarterCount(D.r1a, D.r1b, v1, rb1, occ64, o1)
          + quarterCount(D.r2a, D.r2b, v2, rb2, occ64, o2);
  const int total = waveSum63(cnt);
  if (total < D.thr) {                       // == (float)total/area < 0.5f, by construction
    if (t == 0) accB[D.g] = 1;
    quarterWrite(D.r0a, D.r0b, v0, rb0, occ64, o0);
    quarterWrite(D.r1a, D.r1b, v1, rb1, occ64, o1);
    quarterWrite(D.r2a, D.r2b, v2, rb2, occ64, o2);
  }
}

__global__ void __launch_bounds__(64) k_scan(int* __restrict__ wsI) {
  const int bid = blockIdx.x, t = threadIdx.x;
  if (bid >= NB) {
    // ---- histogram slice (hidden under the serial scan) ----
    __shared__ unsigned int h[2*NC];
    h[t] = 0u;
    __syncthreads();
    const unsigned int* segclsW = (const unsigned int*)((const char*)wsI + (size_t)OFF_SEGCLS*4);
    const int w0 = (bid - NB) * HIST_WORDS;
    const int hb = (w0 >> 16) << 5;            // slice lies in one batch; b*32
    for (int wi = w0 + t; wi < w0 + HIST_WORDS; wi += 64) {
      const unsigned int w = segclsW[wi];
      #pragma unroll
      for (int by = 0; by < 4; ++by) {
        const int cls = (w >> (by*8)) & 0xff;
        if (cls >= 2) atomicAdd(&h[hb + cls], 1u);
      }
    }
    __syncthreads();
    const unsigned int v = h[t];
    if (v) atomicAdd((unsigned int*)&wsI[OFF_COUNTS + t], v);
    return;
  }
  const int b = bid;                          // 1 wave, lockstep, barrier-free main loop
  __shared__ unsigned int occ[OCC_WORDS];     // 53.2 KB (stride 26 -> u64 cells)
  __shared__ int s_list[ND];
  for (int i = t; i < OCC_WORDS; i += 64) occ[i] = 0u;
  // areas / acc-zero (dets t and t+64)
  const int a0 = (t < ND)      ? wsI[OFF_AREA + b*ND + t]      : 0;
  const int a1 = (t + 64 < ND) ? wsI[OFF_AREA + b*ND + t + 64] : 0;
  if (t < ND)      wsI[OFF_ACC + b*ND + t] = 0;
  if (t + 64 < ND) wsI[OFF_ACC + b*ND + t + 64] = 0;
  // ordered compaction of area>0 dets into s_list (sorted-rank order preserved)
  int nact;
  {
    const bool k0 = (t < ND) && (a0 > 0);
    const unsigned long long m0 = __ballot(k0);
    if (k0) s_list[__popcll(m0 & ((1ull << t) - 1ull))] = t;
    nact = (int)__popcll(m0);
    const bool k1 = (t + 64 < ND) && (a1 > 0);
    const unsigned long long m1 = __ballot(k1);
    if (k1) s_list[nact + __popcll(m1 & ((1ull << t) - 1ull))] = t + 64;
    nact += (int)__popcll(m1);
  }
  __syncthreads();
  if (nact == 0) return;
  // pre-permuted per-lane metadata: lane l holds active det l (and l+64)
  int myb0 = 0, maux0 = 0, myb1 = 0, maux1 = 0;
  if (t < nact) {
    const int g = s_list[t];
    myb0 = wsI[OFF_YB + b*ND + g];
    const int q0 = wsI[OFF_QN + b*ND + g] & 0xffff;
    const int area = wsI[OFF_AREA + b*ND + g];
    int c = (area + 1) >> 1;                  // min c with (float)c/area >= 0.5f
    const float a = (float)area;
    while (c > 0 && (float)(c - 1) / a >= 0.5f) --c;
    while ((float)c / a < 0.5f) ++c;
    maux0 = q0 | (g << 4) | (c << 11);
  }
  if (t + 64 < nact) {
    const int g = s_list[t + 64];
    myb1 = wsI[OFF_YB + b*ND + g];
    const int q0 = wsI[OFF_QN + b*ND + g] & 0xffff;
    const int area = wsI[OFF_AREA + b*ND + g];
    int c = (area + 1) >> 1;
    const float a = (float)area;
    while (c > 0 && (float)(c - 1) / a >= 0.5f) --c;
    while ((float)c / a < 0.5f) ++c;
    maux1 = q0 | (g << 4) | (c << 11);
  }
  const ulonglong2* bmp2 = (const ulonglong2*)((unsigned int*)wsI + OFF_BMP8 + (size_t)b*ND*BMP8_DETWORDS);
  unsigned long long* occ64 = (unsigned long long*)occ;
  int* accB = wsI + OFF_ACC + b*ND;
  const int last = nact - 1;
  // uniform metadata access: few-cycle readlane instead of LDS round-trips
  #define MYB(ii)  ((ii) < 64 ? __builtin_amdgcn_readlane(myb0,  (ii)) \
                              : __builtin_amdgcn_readlane(myb1,  (ii) - 64))
  #define MAUX(ii) ((ii) < 64 ? __builtin_amdgcn_readlane(maux0, (ii)) \
                              : __builtin_amdgcn_readlane(maux1, (ii) - 64))
  DetReg A, B, C, D;
  { int i0 = 0;              fetchD(MYB(i0), MAUX(i0), t, bmp2, A); }
  { int i1 = min(1, last);   fetchD(MYB(i1), MAUX(i1), t, bmp2, B); }
  { int i2 = min(2, last);   fetchD(MYB(i2), MAUX(i2), t, bmp2, C); }
  { int i3 = min(3, last);   fetchD(MYB(i3), MAUX(i3), t, bmp2, D); }
  for (int ii = 0; ii < nact; ii += 4) {
    processDet(t, A, occ64, accB);
    { const int n = min(ii + 4, last); fetchD(MYB(n), MAUX(n), t, bmp2, A); }
    if (ii + 1 < nact) processDet(t, B, occ64, accB);
    { const int n = min(ii + 5, last); fetchD(MYB(n), MAUX(n), t, bmp2, B); }
    if (ii + 2 < nact) processDet(t, C, occ64, accB);
    { const int n = min(ii + 6, last); fetchD(MYB(n), MAUX(n), t, bmp2, C); }
    if (ii + 3 < nact) processDet(t, D, occ64, accB);
    { const int n = min(ii + 7, last); fetchD(MYB(n), MAUX(n), t, bmp2, D); }
  }
  #undef MYB
  #undef MAUX
}

// ================= K3: paint owners via atomicMin, 4 rows per iteration =================
__global__ void __launch_bounds__(1024) k_paint(const int* __restrict__ wsI,
                                                int* __restrict__ out) {
  const int g = blockIdx.x;             // b*ND + k
  if (!wsI[OFF_ACC + g]) return;        // uniform
  const int t = threadIdx.x;            // 1024 = 4 rows x 8 words x 32 bits
  const int b = g / ND, k = g - b*ND;
  const int yb = wsI[OFF_YB + g];
  const int ylo = yb & 0xffff;
  const int rows = (yb >> 16) - ylo;
  const int q0 = wsI[OFF_QN + g] & 0xffff;   // even-aligned base word
  const unsigned int* bmp = (const unsigned int*)wsI + OFF_BMP8 + g*BMP8_DETWORDS;
  int* __restrict__ owner = out + b*(OH*OW);     // plane 0 doubles as owner map
  const int rq = t >> 8;                // row quarter 0..3
  const int px = t & 255;
  const int iw = px >> 5, bit = px & 31;
  const int x = ((q0 + iw) << 5) + bit;
  if (x >= OW) return;                  // pad-word lanes carry zero bits
  #pragma unroll 2
  for (int r = rq; r < rows; r += 4) {
    const unsigned int wv = bmp[r*BMP8_ROWWORDS + iw];
    if ((wv >> bit) & 1u)
      atomicMin(&owner[(ylo + r)*OW + x], k);    // owner = min sorted rank == ref
  }
}

// ================= K4: resolve owner -> inst/cat, else stuff (uint4 vectorized) =================
__global__ void k_resolve(const int* __restrict__ wsI, int* __restrict__ out) {
  const int t = threadIdx.x;
  const int q = blockIdx.x*256 + t;      // quad index (4 px)
  const int b = q >> 16;
  __shared__ int s_val[ND];
  __shared__ int s_cnt[NC];
  if (t < ND) s_val[t] = wsI[OFF_VAL + b*ND + t];
  if (t >= 128 && t < 128 + NC) s_cnt[t - 128] = wsI[OFF_COUNTS + b*32 + (t - 128)];
  __syncthreads();
  const uint4 o4 = ((const uint4*)out)[q];
  const unsigned int clsw = ((const unsigned int*)((const char*)wsI + (size_t)OFF_SEGCLS*4))[q];
  uint4 i4, c4;
  {
    const int o = (int)o4.x;
    if (o < ND) { const int v = s_val[o]; i4.x = v & 0xffff; c4.x = v >> 16; }
    else { i4.x = (unsigned)-1; const int cl = clsw & 0xff;
           c4.x = (cl >= 2 && s_cnt[cl] > 4096) ? cl + 90 : 0; }
  }
  {
    const int o = (int)o4.y;
    if (o < ND) { const int v = s_val[o]; i4.y = v & 0xffff; c4.y = v >> 16; }
    else { i4.y = (unsigned)-1; const int cl = (clsw >> 8) & 0xff;
           c4.y = (cl >= 2 && s_cnt[cl] > 4096) ? cl + 90 : 0; }
  }
  {
    const int o = (int)o4.z;
    if (o < ND) { const int v = s_val[o]; i4.z = v & 0xffff; c4.z = v >> 16; }
    else { i4.z = (unsigned)-1; const int cl = (clsw >> 16) & 0xff;
           c4.z = (cl >= 2 && s_cnt[cl] > 4096) ? cl + 90 : 0; }
  }
  {
    const int o = (int)o4.w;
    if (o < ND) { const int v = s_val[o]; i4.w = v & 0xffff; c4.w = v >> 16; }
    else { i4.w = (unsigned)-1; const int cl = (clsw >> 24) & 0xff;
           c4.w = (cl >= 2 && s_cnt[cl] > 4096) ? cl + 90 : 0; }
  }
  ((uint4*)out)[q] = i4;
  ((uint4*)(out + NB*OH*OW))[q] = c4;
}

extern "C" void kernel_launch(void* const* d_in, const int* in_sizes, int n_in,
                              void* d_out, int out_size, void* d_ws, size_t ws_size,
                              hipStream_t stream) {
  const float* boxes   = (const float*)d_in[0];
  const int*   classes = (const int*)d_in[1];
  const float* scores  = (const float*)d_in[2];
  const float* dmasks  = (const float*)d_in[3];
  const float* segp    = (const float*)d_in[4];
  int* wsI = (int*)d_ws;
  int* out = (int*)d_out;

  k_segmask<<<128 + NB*ND, 1024, 0, stream>>>(boxes, classes, scores, dmasks, segp, wsI, out);
  k_scan   <<<NB + NHIST, 64, 0, stream>>>(wsI);
  k_paint  <<<NB*ND, 1024, 0, stream>>>(wsI, out);
  k_resolve<<<(NB*OH*OW)/1024, 256, 0, stream>>>(wsI, out);
}